// Round 11
// baseline (285.658 us; speedup 1.0000x reference)
//
#include <hip/hip_runtime.h>
#include <hip/hip_bf16.h>
#include <math.h>

#define BS 4
#define CIN 256
#define HF 56
#define WF 120
#define CF 64
#define DD 48
#define HW (HF*WF)          // 6720
#define BEVX 128
#define BEVY 128
#define NCELL (BEVX*BEVY)   // 16384
#define NPTS (DD*HW)        // 322560

#define PH 60               // padded rows
#define PW 124              // padded cols

#define PACKW_BLOCKS 400             // 102400 threads
#define CELL_BLOCKS  23              // 5760 (w,d) pairs / 256

typedef short s16x8 __attribute__((ext_vector_type(8)));
typedef float f32x4 __attribute__((ext_vector_type(4)));

__device__ __forceinline__ unsigned short f2bf(float f) {
    unsigned int u = __float_as_uint(f);
    unsigned int r = (u + 0x7FFFu + ((u >> 16) & 1u)) >> 16;
    return (unsigned short)r;
}
__device__ __forceinline__ float bf2f(unsigned short s) {
    return __uint_as_float(((unsigned int)s) << 16);
}

// ---------------- pad: f32 (b,ci,h,w) -> bf16 (b,h+2,w+2,ci), LDS-transposed ----------------
__global__ __launch_bounds__(256) void pad_kernel(
    const float* __restrict__ state, unsigned short* __restrict__ P)
{
    __shared__ float lt[32 * 257];
    const int tile = blockIdx.x;
    const int b    = blockIdx.y;
    const int tid  = threadIdx.x;
    const int4 z4 = make_int4(0, 0, 0, 0);

    if (tile < 210) {
        const int hw0 = tile * 32;
        const int wl = tid & 31;
        const int cg = tid >> 5;          // 0..7
        const float* src = state + (size_t)(b * CIN + cg * 32) * HW + hw0 + wl;
#pragma unroll 8
        for (int k = 0; k < 32; ++k)
            lt[wl * 257 + cg * 32 + k] = src[(size_t)k * HW];
        __syncthreads();

        const int px = tid >> 3;          // 0..31
        const int ck = tid & 7;           // 16B chunk
        const int hw = hw0 + px;
        const int h = hw / WF, w = hw - h * WF;
        unsigned short* dst = P + (((size_t)b * PH + h + 2) * PW + (w + 2)) * CIN;
#pragma unroll
        for (int r = 0; r < 4; ++r) {
            const int c0 = r * 64 + ck * 8;
            unsigned short tmp[8];
#pragma unroll
            for (int j = 0; j < 8; ++j) tmp[j] = f2bf(lt[px * 257 + c0 + j]);
            *(int4*)(dst + c0) = *(const int4*)tmp;
        }
    } else {
        // border pixels: 720 per image
        const int pxid = (tile - 210) * 32 + (tid >> 3);
        const int ck = tid & 7;
        if (pxid < 720) {
            int h2, w2;
            if (pxid < 496) { int r = pxid / 124; h2 = (r < 2) ? r : 56 + r; w2 = pxid - r * 124; }
            else { int u = pxid - 496; h2 = 2 + (u >> 2); int m = u & 3; w2 = (m < 2) ? m : 120 + m; }
            unsigned short* dst = P + (((size_t)b * PH + h2) * PW + w2) * CIN;
#pragma unroll
            for (int r = 0; r < 4; ++r)
                *(int4*)(dst + r * 64 + ck * 8) = z4;
        }
    }
}

// ---------------- prep: weight pack + aff/Wd + cell table ----------------
__global__ __launch_bounds__(256) void prep_kernel(
    const float* __restrict__ intr, const float* __restrict__ extr,
    const float* __restrict__ fw, const float* __restrict__ dw,
    const float* __restrict__ fb, const float* __restrict__ fg, const float* __restrict__ fbt,
    const float* __restrict__ db, const float* __restrict__ dg, const float* __restrict__ dbt,
    const float* __restrict__ dpw,
    unsigned short* __restrict__ Wf, float2* __restrict__ aff,
    unsigned short* __restrict__ Wd, int* __restrict__ celltab)
{
    const int bid = blockIdx.x;
    const int tid = threadIdx.x;

    if (bid < PACKW_BLOCKS) {
        // ---- conv weight pack ----
        int t = bid * 256 + tid;
        int lane = t & 63;
        int nf = (t >> 6) & 7;
        int kc = (t >> 9) & 7;
        int p  = t >> 12;
        int n   = nf * 16 + (lane & 15);
        int ci0 = kc * 32 + (lane >> 4) * 8;
        const float* src = (n < 64) ? fw + (size_t)n * CIN * 25
                                    : dw + (size_t)(n - 64) * CIN * 25;
        unsigned short v[8];
#pragma unroll
        for (int j = 0; j < 8; ++j)
            v[j] = f2bf(src[(size_t)(ci0 + j) * 25 + p]);
        *(int4*)(Wf + (size_t)t * 8) = *(const int4*)v;
    } else if (bid == PACKW_BLOCKS) {
        // ---- affine pack + depth-weight B-fragments ----
        if (tid < 128) {
            float g, bi, bt;
            if (tid < 64) { g = fg[tid]; bi = fb[tid]; bt = fbt[tid]; }
            else          { g = dg[tid - 64]; bi = db[tid - 64]; bt = dbt[tid - 64]; }
            aff[tid] = make_float2(g, g * bi + bt);
        }
        for (int e = tid; e < 384; e += 256) {
            int ln = e & 63;
            int s  = (e >> 6) & 1;
            int t  = e >> 7;
            unsigned short v[8];
#pragma unroll
            for (int j = 0; j < 8; ++j)
                v[j] = f2bf(dpw[(16 * t + (ln & 15)) * CF + s * 32 + (ln >> 4) * 8 + j]);
            *(int4*)(Wd + (size_t)e * 8) = *(const int4*)v;
        }
    } else {
        // ---- cell table: byte-identical geometry numerics, evaluated per (d,w) ----
        int pair = (bid - PACKW_BLOCKS - 1) * 256 + tid;
        if (pair >= DD * WF) return;
        int d = pair / WF;
        int w = pair - d * WF;
        int h = 0;                        // geometry is bit-exactly h-independent

        float k00 = intr[0], k01 = intr[1], k02 = intr[2];
        float k11 = intr[4], k12 = intr[5];
        float k22 = intr[8];

        float A00 = __fdiv_rn(1.0f, k00);
        float A11 = __fdiv_rn(1.0f, k11);
        float A01 = __fmul_rn(__fmul_rn(k01, A00), -A11);
        float A22 = __fdiv_rn(1.0f, k22);
        float x0  = __fmul_rn(k02, A00);
        x0        = __fadd_rn(x0, __fmul_rn(k12, A01));
        float x1  = __fmul_rn(k12, A11);
        float A02 = __fmul_rn(x0, -A22);
        float A12 = __fmul_rn(x1, -A22);

        float i00 = A00, i01 = A01, i02 = A02;
        float i10 = 0.f, i11 = A11, i12 = A12;
        float i20 = 0.f, i21 = 0.f, i22 = A22;

        float u   = (w + 0.5f) * 8.0f;
        float v   = (h + 0.5f) * 8.0f;
        float dsv = 2.0f + (float)d;
        float px  = __fmul_rn(u, dsv);
        float py  = __fmul_rn(v, dsv);
        float pz  = dsv;

        float cam0 = fmaf(pz, i02, fmaf(py, i01, fmaf(px, i00, 0.0f)));
        float cam1 = fmaf(pz, i12, fmaf(py, i11, fmaf(px, i10, 0.0f)));
        float cam2 = fmaf(pz, i22, fmaf(py, i21, fmaf(px, i20, 0.0f)));

        float r00 = extr[0], r01 = extr[1], r02 = extr[2],  t0 = extr[3];
        float r10 = extr[4], r11 = extr[5], r12 = extr[6],  t1 = extr[7];

        float mm0 = fmaf(cam2, r02, fmaf(cam1, r01, fmaf(cam0, r00, 0.0f)));
        float mm1 = fmaf(cam2, r12, fmaf(cam1, r11, fmaf(cam0, r10, 0.0f)));
        float e0  = __fadd_rn(mm0, t0);
        float e1  = __fadd_rn(mm1, t1);

        float ixf = floorf(__fadd_rn(__fadd_rn(__fdiv_rn(e0, 0.6f), 32.0f), 64.0f));
        float iyf = floorf(__fadd_rn(__fdiv_rn(e1, 0.6f), 64.0f));
        int ix = (int)ixf;
        int iy = (int)iyf;

        bool valid = (ix >= 0) && (ix < BEVX) && (iy >= 0) && (iy < BEVY);
        celltab[pair] = valid ? iy * BEVX + ix : -1;
    }
}

// ---------------- conv via MFMA implicit GEMM: 8 waves, tap-split, 64-ch waves ----------------
// grid (15,7,BS), 512 thr. Block: 64 px (8x8) x 128 out-ch.
// Wave (tp, wn, wm): taps {0..12 | 13..24}, ch-half 64, px-half 32. 8 MFMA per 2 ds_read.
// End: tap-halves reduced via LDS, tp=0 waves do epilogue.
#define CONV_TAPS(PL, PH_)                                                              \
    for (int p = PL; p < PH_; ++p) {                                                    \
        const int poff = (p / 5) * 12 + (p % 5);                                        \
        const int px0 = pb0 + poff;                                                     \
        const int px1 = pb1 + poff;                                                     \
        s16x8 a0 = *(const s16x8*)(lb + px0 * 32 + (kg ^ ((px0 >> 1) & 3)) * 8);        \
        s16x8 a1 = *(const s16x8*)(lb + px1 * 32 + (kg ^ ((px1 >> 1) & 3)) * 8);        \
        const unsigned short* wp =                                                      \
            Wf + ((((size_t)(p * 8 + kc)) * 8 + wn * 4) * 64 + lane) * 8;               \
        s16x8 b0 = *(const s16x8*)(wp);                                                 \
        s16x8 b1 = *(const s16x8*)(wp + 512);                                           \
        s16x8 b2 = *(const s16x8*)(wp + 1024);                                          \
        s16x8 b3 = *(const s16x8*)(wp + 1536);                                          \
        acc[0][0] = __builtin_amdgcn_mfma_f32_16x16x32_bf16(a0, b0, acc[0][0], 0, 0, 0);\
        acc[1][0] = __builtin_amdgcn_mfma_f32_16x16x32_bf16(a1, b0, acc[1][0], 0, 0, 0);\
        acc[0][1] = __builtin_amdgcn_mfma_f32_16x16x32_bf16(a0, b1, acc[0][1], 0, 0, 0);\
        acc[1][1] = __builtin_amdgcn_mfma_f32_16x16x32_bf16(a1, b1, acc[1][1], 0, 0, 0);\
        acc[0][2] = __builtin_amdgcn_mfma_f32_16x16x32_bf16(a0, b2, acc[0][2], 0, 0, 0);\
        acc[1][2] = __builtin_amdgcn_mfma_f32_16x16x32_bf16(a1, b2, acc[1][2], 0, 0, 0);\
        acc[0][3] = __builtin_amdgcn_mfma_f32_16x16x32_bf16(a0, b3, acc[0][3], 0, 0, 0);\
        acc[1][3] = __builtin_amdgcn_mfma_f32_16x16x32_bf16(a1, b3, acc[1][3], 0, 0, 0);\
    }

__global__ __launch_bounds__(512) void conv_mfma_kernel(
    const unsigned short* __restrict__ P, const unsigned short* __restrict__ Wf,
    const float2* __restrict__ aff,
    unsigned short* __restrict__ xTb, unsigned short* __restrict__ decB)
{
    __shared__ __align__(16) unsigned short lds[2][144 * 32];   // 18432 B
    __shared__ __align__(16) float red[4 * 8 * 64 * 4];         // 32768 B

    const int tid  = threadIdx.x;
    const int lane = tid & 63;
    const int wid  = tid >> 6;        // 0..7
    const int tp   = wid >> 2;        // tap half
    const int wn   = (wid >> 1) & 1;  // ch half
    const int wm   = wid & 1;         // px half
    const int b  = blockIdx.z;
    const int h0 = blockIdx.y * 8;
    const int w0 = blockIdx.x * 8;

    const unsigned short* Pb = P + (((size_t)b * PH + h0) * PW + w0) * CIN;

    // staging: 576 chunks of 16B; thread covers tid, and 512+tid for tid<64
    const int pix0 = tid >> 2,          slot0 = tid & 3;
    const size_t g0 = ((size_t)(pix0 / 12) * PW + (pix0 % 12)) * CIN + slot0 * 8;
    const int l0 = pix0 * 32 + (slot0 ^ ((pix0 >> 1) & 3)) * 8;
    const int c1 = 512 + tid;
    const int pix1 = c1 >> 2,           slot1 = c1 & 3;
    const size_t g1 = ((size_t)(pix1 / 12) * PW + (pix1 % 12)) * CIN + slot1 * 8;
    const int l1 = pix1 * 32 + (slot1 ^ ((pix1 >> 1) & 3)) * 8;
    const bool has2 = (tid < 64);

    f32x4 acc[2][4];
#pragma unroll
    for (int i = 0; i < 2; ++i)
#pragma unroll
        for (int j = 0; j < 4; ++j)
            acc[i][j] = (f32x4){0.f, 0.f, 0.f, 0.f};

    const int kg = lane >> 4;
    const int m0 = wm * 32 + (lane & 15);
    const int m1 = m0 + 16;
    const int pb0 = ((m0 >> 3)) * 12 + (m0 & 7);
    const int pb1 = ((m1 >> 3)) * 12 + (m1 & 7);

    // prologue: stage kc=0
    {
        int4 r0 = *(const int4*)(Pb + g0);
        int4 r1;
        if (has2) r1 = *(const int4*)(Pb + g1);
        *(int4*)((char*)lds[0] + (size_t)l0 * 2) = r0;
        if (has2) *(int4*)((char*)lds[0] + (size_t)l1 * 2) = r1;
    }
    __syncthreads();

    for (int kc = 0; kc < 8; ++kc) {
        const int cur = kc & 1;
        int4 n0, n1;
        if (kc < 7) {
            n0 = *(const int4*)(Pb + g0 + (size_t)(kc + 1) * 32);
            if (has2) n1 = *(const int4*)(Pb + g1 + (size_t)(kc + 1) * 32);
        }
        const unsigned short* lb = lds[cur];
        if (tp == 0) { CONV_TAPS(0, 13) } else { CONV_TAPS(13, 25) }
        if (kc < 7) {
            *(int4*)((char*)lds[cur ^ 1] + (size_t)l0 * 2) = n0;
            if (has2) *(int4*)((char*)lds[cur ^ 1] + (size_t)l1 * 2) = n1;
        }
        __syncthreads();
    }

    // tap-half reduction
    const int pair = wm * 2 + wn;
    if (tp == 1) {
#pragma unroll
        for (int mf = 0; mf < 2; ++mf)
#pragma unroll
            for (int nf = 0; nf < 4; ++nf)
                *(f32x4*)&red[((pair * 8 + mf * 4 + nf) * 64 + lane) * 4] = acc[mf][nf];
    }
    __syncthreads();
    if (tp == 1) return;

#pragma unroll
    for (int mf = 0; mf < 2; ++mf)
#pragma unroll
        for (int nf = 0; nf < 4; ++nf) {
            f32x4 o = *(const f32x4*)&red[((pair * 8 + mf * 4 + nf) * 64 + lane) * 4];
            acc[mf][nf] += o;
        }

    // epilogue: affine + relu -> bf16, channel-last (b,hw,64)
#pragma unroll
    for (int nf = 0; nf < 4; ++nf) {
        const int n = wn * 64 + nf * 16 + (lane & 15);
        const float2 sc = aff[n];
        unsigned short* dst = (n < 64) ? xTb : decB;
        const int ch = n & 63;
#pragma unroll
        for (int mf = 0; mf < 2; ++mf) {
#pragma unroll
            for (int r = 0; r < 4; ++r) {
                const int m = wm * 32 + mf * 16 + (lane >> 4) * 4 + r;
                const int h = h0 + (m >> 3), w = w0 + (m & 7);
                dst[(((size_t)b * HW) + h * WF + w) * 64 + ch] =
                    f2bf(fmaxf(sc.x * acc[mf][nf][r] + sc.y, 0.f));
            }
        }
    }
}

// ---------------- depth head: MFMA 1x1 conv (64->48) + in-wave softmax + pooled zero ----------------
__global__ __launch_bounds__(256) void depth_kernel(
    const unsigned short* __restrict__ decB, const unsigned short* __restrict__ Wd,
    const float* __restrict__ dbs, float* __restrict__ depP, float4* __restrict__ poolz)
{
    {
        const int gid = blockIdx.x * 256 + threadIdx.x;
        const float4 z = make_float4(0.f, 0.f, 0.f, 0.f);
#pragma unroll
        for (int r = 0; r < 10; ++r) {
            int i = gid + r * (420 * 256);
            if (i < (BS * NCELL * CF) / 4) poolz[i] = z;
        }
    }

    const int lane = threadIdx.x & 63;
    const int wave = blockIdx.x * 4 + (threadIdx.x >> 6);   // 0..1679
    const int px0  = wave * 16;

    const unsigned short* A = decB + (size_t)px0 * 64 + (lane & 15) * 64 + (lane >> 4) * 8;
    s16x8 a0 = *(const s16x8*)(A);
    s16x8 a1 = *(const s16x8*)(A + 32);

    f32x4 acc[3];
    float dbv[3];
#pragma unroll
    for (int t = 0; t < 3; ++t) {
        acc[t] = (f32x4){0.f, 0.f, 0.f, 0.f};
        dbv[t] = dbs[16 * t + (lane & 15)];
        s16x8 b0 = *(const s16x8*)(Wd + ((size_t)(t * 2 + 0) * 64 + lane) * 8);
        s16x8 b1 = *(const s16x8*)(Wd + ((size_t)(t * 2 + 1) * 64 + lane) * 8);
        acc[t] = __builtin_amdgcn_mfma_f32_16x16x32_bf16(a0, b0, acc[t], 0, 0, 0);
        acc[t] = __builtin_amdgcn_mfma_f32_16x16x32_bf16(a1, b1, acc[t], 0, 0, 0);
    }

#pragma unroll
    for (int r = 0; r < 4; ++r) {
        float l0 = acc[0][r] + dbv[0];
        float l1 = acc[1][r] + dbv[1];
        float l2 = acc[2][r] + dbv[2];
        float m = fmaxf(fmaxf(l0, l1), l2);
#pragma unroll
        for (int o = 1; o < 16; o <<= 1) m = fmaxf(m, __shfl_xor(m, o));
        float e0 = expf(l0 - m), e1 = expf(l1 - m), e2 = expf(l2 - m);
        float s = e0 + e1 + e2;
#pragma unroll
        for (int o = 1; o < 16; o <<= 1) s += __shfl_xor(s, o);
        float inv = 1.0f / s;
        float* op = depP + (size_t)(px0 + (lane >> 4) * 4 + r) * DD + (lane & 15);
        op[0]  = e0 * inv;
        op[16] = e1 * inv;
        op[32] = e2 * inv;
    }
}

// ---------------- colsum: dense h-reduction per (w,d), scatter per cell ----------------
__global__ __launch_bounds__(256) void colsum_kernel(
    const unsigned short* __restrict__ xTb, const float* __restrict__ depP,
    const int* __restrict__ celltab, float* __restrict__ pooled)
{
    const int w  = blockIdx.x;
    const int b  = blockIdx.z;
    const int lane = threadIdx.x & 63;
    const int wv   = threadIdx.x >> 6;
    const int dbase = blockIdx.y * 16 + wv * 4;

    int cells[4];
    bool anyv = false;
#pragma unroll
    for (int j = 0; j < 4; ++j) {
        cells[j] = celltab[(dbase + j) * WF + w];
        anyv |= (cells[j] >= 0);
    }
    if (!anyv) return;

    const unsigned short* xp = xTb + (((size_t)b * HW) + w) * 64 + lane;
    const float* dp = depP + (((size_t)b * HW) + w) * DD + dbase;

    float acc[4] = {0.f, 0.f, 0.f, 0.f};
#pragma unroll 8
    for (int h = 0; h < HF; ++h) {
        float xv = bf2f(xp[(size_t)h * WF * 64]);
        float4 dv = *(const float4*)(dp + (size_t)h * WF * DD);
        acc[0] = fmaf(dv.x, xv, acc[0]);
        acc[1] = fmaf(dv.y, xv, acc[1]);
        acc[2] = fmaf(dv.z, xv, acc[2]);
        acc[3] = fmaf(dv.w, xv, acc[3]);
    }

    float* pb = pooled + (size_t)b * NCELL * CF;
#pragma unroll
    for (int j = 0; j < 4; ++j)
        if (cells[j] >= 0)
            atomicAdd(&pb[(size_t)cells[j] * CF + lane], acc[j]);
}

// ---------------- transpose pooled (b,cell,64) -> out (b,64,cell) ----------------
__global__ __launch_bounds__(256) void transpose_kernel(
    const float* __restrict__ pooled, float* __restrict__ out)
{
    __shared__ float t[64][65];
    const int b  = blockIdx.y;
    const int c0 = blockIdx.x * 64;
    const int tid = threadIdx.x;
#pragma unroll
    for (int k = 0; k < 16; ++k) {
        int idx = tid + k * 256;
        int cell = idx >> 6, ch = idx & 63;
        t[cell][ch] = pooled[(((size_t)b * NCELL) + c0 + cell) * CF + ch];
    }
    __syncthreads();
#pragma unroll
    for (int k = 0; k < 16; ++k) {
        int idx = tid + k * 256;
        int ch = idx >> 6, cell = idx & 63;
        out[((size_t)b * CF + ch) * NCELL + c0 + cell] = t[cell][ch];
    }
}

// ---------------- launch ----------------
extern "C" void kernel_launch(void* const* d_in, const int* in_sizes, int n_in,
                              void* d_out, int out_size, void* d_ws, size_t ws_size,
                              hipStream_t stream)
{
    const float* state   = (const float*)d_in[0];
    const float* intr    = (const float*)d_in[1];
    const float* extr    = (const float*)d_in[2];
    const float* feat_w  = (const float*)d_in[3];
    const float* feat_b  = (const float*)d_in[4];
    const float* feat_g  = (const float*)d_in[5];
    const float* feat_bt = (const float*)d_in[6];
    const float* dec_w   = (const float*)d_in[7];
    const float* dec_b   = (const float*)d_in[8];
    const float* dec_g   = (const float*)d_in[9];
    const float* dec_bt  = (const float*)d_in[10];
    const float* depth_w = (const float*)d_in[11];
    const float* depth_b = (const float*)d_in[12];
    float* out = (float*)d_out;

    // workspace carve-up (pooled aliases P+Wf, dead after conv)
    char* ws = (char*)d_ws;
    const size_t P_BYTES   = (size_t)BS * PH * PW * CIN * 2;   // 15,237,120
    const size_t WF_BYTES  = (size_t)25 * 8 * 8 * 64 * 16;     // 1,638,400
    const size_t AFF_BYTES = 1024;
    const size_t WD_BYTES  = 384 * 16;                         // 6,144
    const size_t FB_BYTES  = (size_t)BS * HW * CF * 2;         // 3,440,640 (bf16)
    const size_t DEP_BYTES = (size_t)BS * HW * DD * 4;         // 5,160,960
    const size_t CT_BYTES  = ((size_t)DD * WF + 64) * 4;       // cell table

    unsigned short* P    = (unsigned short*)ws;           ws += P_BYTES;
    unsigned short* Wfr  = (unsigned short*)ws;           ws += WF_BYTES;
    float2*         aff  = (float2*)ws;                   ws += AFF_BYTES;
    unsigned short* Wd   = (unsigned short*)ws;           ws += WD_BYTES;
    unsigned short* xTb  = (unsigned short*)ws;           ws += FB_BYTES;
    unsigned short* decB = (unsigned short*)ws;           ws += FB_BYTES;
    float*          depP = (float*)ws;                    ws += DEP_BYTES;
    int*            celltab = (int*)ws;                   ws += CT_BYTES;

    float* pooled = (float*)d_ws;   // 16.78MB, inside P+Wf (16.88MB)

    pad_kernel<<<dim3(233, BS), 256, 0, stream>>>(state, P);

    prep_kernel<<<PACKW_BLOCKS + 1 + CELL_BLOCKS, 256, 0, stream>>>(
        intr, extr, feat_w, dec_w,
        feat_b, feat_g, feat_bt, dec_b, dec_g, dec_bt, depth_w,
        Wfr, aff, Wd, celltab);

    conv_mfma_kernel<<<dim3(15, 7, BS), 512, 0, stream>>>(
        P, Wfr, aff, xTb, decB);

    depth_kernel<<<420, 256, 0, stream>>>(decB, Wd, depth_b, depP, (float4*)pooled);

    colsum_kernel<<<dim3(WF, 3, BS), 256, 0, stream>>>(xTb, depP, celltab, pooled);

    transpose_kernel<<<dim3(NCELL / 64, BS), 256, 0, stream>>>(pooled, out);
}